// Round 12
// baseline (487.912 us; speedup 1.0000x reference)
//
#include <hip/hip_runtime.h>
#include <hip/hip_bf16.h>

#define N_NODES 100000
#define NEDGE   600000
#define SCAN_B  1024
#define NBLK    98            // ceil(N_NODES / SCAN_B)
#define BSHIFT  9             // bucket = dst >> 9 (512 nodes/bucket)
#define NBUCK   196           // ceil(N_NODES / 512)
#define BCAP    3456          // per (rel,bucket) staging cap (mean 3061 + 7 sigma)
#define PADCAP  1400000       // per-rel padded csr cap (hard bound 8*N + E = 1.4M)
#define ZROW    N_NODES       // zero-row index in (N+1)-row source buffers

typedef __attribute__((ext_vector_type(8))) short bf16x8;
typedef __attribute__((ext_vector_type(4))) short s16x4;
typedef __attribute__((ext_vector_type(4))) float f32x4;
typedef __attribute__((ext_vector_type(4))) unsigned u32x4;

__device__ __forceinline__ short f2bf(float f) {
  union { float f; unsigned u; } x; x.f = f;
  unsigned r = x.u + 0x7FFFu + ((x.u >> 16) & 1u);
  return (short)(r >> 16);
}

// packed bf16 convert: D = [bf16(lo), bf16(hi)] in one instruction (RNE)
__device__ __forceinline__ unsigned cvtpk(float lo, float hi) {
  unsigned r;
  asm("v_cvt_pk_bf16_f32 %0, %1, %2" : "=v"(r) : "v"(lo), "v"(hi));
  return r;
}

// Phase A: bin edges into 196 per-bucket segments. Packed entry:
// bits 0..16 = src (max 99999 < 2^17), bits 17..25 = dst & 511.
__global__ __launch_bounds__(256) void bin_k(const int* __restrict__ sidx,
                                             const int* __restrict__ didx,
                                             int* __restrict__ bincnt,
                                             unsigned* __restrict__ stage) {
  __shared__ int hist[NBUCK];
  __shared__ int base[NBUCK];
  int r = blockIdx.y, t = threadIdx.x;
  int e0 = blockIdx.x * 2048 + t;
  const int* dd = didx + (size_t)r * NEDGE;
  const int* ss = sidx + (size_t)r * NEDGE;
  for (int i = t; i < NBUCK; i += 256) hist[i] = 0;
  __syncthreads();
  unsigned pv[8]; int bu[8], lr[8];
#pragma unroll
  for (int j = 0; j < 8; ++j) {
    int e = e0 + j * 256;
    if (e < NEDGE) {
      int dv = dd[e];
      bu[j] = dv >> BSHIFT;
      pv[j] = (unsigned)ss[e] | ((unsigned)(dv & 511) << 17);
      lr[j] = atomicAdd(&hist[bu[j]], 1);     // LDS atomic
    }
  }
  __syncthreads();
  for (int i = t; i < NBUCK; i += 256)
    base[i] = atomicAdd(&bincnt[r * NBUCK + i], hist[i]);
  __syncthreads();
#pragma unroll
  for (int j = 0; j < 8; ++j) {
    int e = e0 + j * 256;
    if (e < NEDGE)
      stage[(size_t)(r * NBUCK + bu[j]) * BCAP + base[bu[j]] + lr[j]] = pv[j];
  }
}

// Phase B: one block per (bucket, rel): LDS histogram, coalesced cnt write.
__global__ __launch_bounds__(256) void hist_k(const unsigned* __restrict__ stage,
                                              const int* __restrict__ bincnt,
                                              int* __restrict__ cnt) {
  __shared__ int h[512];
  int bu = blockIdx.x, r = blockIdx.y, t = threadIdx.x;
  int len = bincnt[r * NBUCK + bu];
  const unsigned* sg = stage + (size_t)(r * NBUCK + bu) * BCAP;
  h[t] = 0; h[t + 256] = 0;
  __syncthreads();
  for (int i = t; i < len; i += 256) atomicAdd(&h[sg[i] >> 17], 1);  // LDS
  __syncthreads();
  int lo = bu << BSHIFT;
  int d0 = lo + t;
  if (d0 < N_NODES)       cnt[r * N_NODES + d0]       = h[t];
  if (d0 + 256 < N_NODES) cnt[r * N_NODES + d0 + 256] = h[t + 256];
}

__device__ __forceinline__ int padlen8(int c) {
  int p = (c + 7) & ~7;
  return p < 8 ? 8 : p;   // min 8 so the gather fast path is unconditional
}

// Phase 1: per-block chunk sums of PADDED counts.
__global__ __launch_bounds__(256) void scan1_k(const int* __restrict__ cnt,
                                               int* __restrict__ bsum) {
  __shared__ int lds[256];
  int b = blockIdx.x, r = blockIdx.y, t = threadIdx.x;
  int i0 = b * SCAN_B + t * 4;
  int s = 0;
#pragma unroll
  for (int j = 0; j < 4; ++j)
    if (i0 + j < N_NODES) s += padlen8(cnt[r * N_NODES + i0 + j]);
  lds[t] = s;
  __syncthreads();
  for (int st = 128; st > 0; st >>= 1) {
    if (t < st) lds[t] += lds[t + st];
    __syncthreads();
  }
  if (t == 0) bsum[r * NBLK + b] = lds[0];
}

__global__ __launch_bounds__(128) void scan2_k(int* __restrict__ bsum) {
  __shared__ int buf[128];
  int t = threadIdx.x;
  for (int r = 0; r < 4; ++r) {
    int v = (t < NBLK) ? bsum[r * NBLK + t] : 0;
    buf[t] = v;
    __syncthreads();
    for (int st = 1; st < 128; st <<= 1) {
      int x = (t >= st) ? buf[t - st] : 0;
      __syncthreads();
      buf[t] += x;
      __syncthreads();
    }
    if (t < NBLK) bsum[r * NBLK + t] = buf[t] - v;   // exclusive
    __syncthreads();
  }
}

// Phase 3: padded exclusive scan -> offp (all offsets multiples of 8).
__global__ __launch_bounds__(256) void scan3_k(const int* __restrict__ cnt,
                                               const int* __restrict__ bsum,
                                               int* __restrict__ offp) {
  __shared__ int lds[256];
  int b = blockIdx.x, r = blockIdx.y, t = threadIdx.x;
  int i0 = b * SCAN_B + t * 4;
  int c[4] = {0, 0, 0, 0};
#pragma unroll
  for (int j = 0; j < 4; ++j)
    if (i0 + j < N_NODES) c[j] = padlen8(cnt[r * N_NODES + i0 + j]);
  int s = c[0] + c[1] + c[2] + c[3];
  lds[t] = s;
  __syncthreads();
  for (int st = 1; st < 256; st <<= 1) {
    int x = (t >= st) ? lds[t - st] : 0;
    __syncthreads();
    lds[t] += x;
    __syncthreads();
  }
  int run = bsum[r * NBLK + b] + lds[t] - s;
  int* o = offp + r * (N_NODES + 1);
#pragma unroll
  for (int j = 0; j < 4; ++j) {
    int i = i0 + j;
    if (i < N_NODES) {
      o[i] = run; run += c[j];
      if (i == N_NODES - 1) o[N_NODES] = run;
    }
  }
}

// Phase C: place edges with LDS-only cursors at padded offsets.
__global__ __launch_bounds__(256) void place_k(const unsigned* __restrict__ stage,
                                               const int* __restrict__ bincnt,
                                               const int* __restrict__ offp,
                                               int* __restrict__ csrp) {
  __shared__ int ofl[512];
  __shared__ int cur[512];
  int bu = blockIdx.x, r = blockIdx.y, t = threadIdx.x;
  int len = bincnt[r * NBUCK + bu];
  const unsigned* sg = stage + (size_t)(r * NBUCK + bu) * BCAP;
  const int* of = offp + r * (N_NODES + 1);
  int* cs = csrp + (size_t)r * PADCAP;
  int lo = bu << BSHIFT;
  int d0 = lo + t;
  ofl[t]       = (d0 < N_NODES) ? of[d0] : 0;
  ofl[t + 256] = (d0 + 256 < N_NODES) ? of[d0 + 256] : 0;
  cur[t] = 0; cur[t + 256] = 0;
  __syncthreads();
  for (int i = t; i < len; i += 256) {
    unsigned v = sg[i];
    int dl = v >> 17;
    int pos = ofl[dl] + atomicAdd(&cur[dl], 1);   // LDS atomic
    cs[pos] = (int)(v & 0x1FFFFu);
  }
}

// Fill padded tail slots with the zero-row index.
__global__ __launch_bounds__(256) void padfill_k(const int* __restrict__ cnt,
                                                 const int* __restrict__ offp,
                                                 int* __restrict__ csrp) {
  int n = blockIdx.x * 256 + threadIdx.x;
  int r = blockIdx.y;
  if (n >= N_NODES) return;
  int d = cnt[r * N_NODES + n];
  const int* o = offp + r * (N_NODES + 1);
  int p = o[n] + d, p1 = o[n + 1];
  int* cs = csrp + (size_t)r * PADCAP;
  for (; p < p1; ++p) cs[p] = ZROW;
}

// f32 -> packed bf16 for both inputs in one dispatch (blockIdx.y selects).
__global__ __launch_bounds__(256) void cvt2_k(const float* __restrict__ x0,
                                              const float* __restrict__ x1,
                                              unsigned* __restrict__ o0,
                                              unsigned* __restrict__ o1) {
  const float* x = blockIdx.y ? x1 : x0;
  unsigned* o = blockIdx.y ? o1 : o0;
  int i = blockIdx.x * 256 + threadIdx.x;     // i < N_NODES*16
  if (i >= N_NODES * 16) return;
  f32x4 v0 = ((const f32x4*)x)[i * 2];
  f32x4 v1 = ((const f32x4*)x)[i * 2 + 1];
  ((u32x4*)o)[i] = (u32x4){cvtpk(v0[0], v0[1]), cvtpk(v0[2], v0[3]),
                           cvtpk(v1[0], v1[1]), cvtpk(v1[2], v1[3])};
}

// Pack combined weights into MFMA B-fragment-linear layout.
__global__ __launch_bounds__(256) void prep_w_k(const float* __restrict__ Ws1,
                                                const float* __restrict__ Wn1,
                                                const float* __restrict__ Ws2,
                                                const float* __restrict__ Wn2,
                                                short* __restrict__ WTp) {
  int tid = blockIdx.x * 256 + threadIdx.x;  // 0..98303
  int lane = tid & 63;
  int n0 = (tid >> 6) & 7;
  int idx3 = tid >> 9;
  int k0 = idx3 % 12;
  int lt = idx3 / 12;
  int l = lt >> 1, t = lt & 1;
  const float* Wself  = l ? Ws2 : Ws1;
  const float* Wneigh = l ? Wn2 : Wn1;
  int rA = t ? 0 : 1, rB = t ? 3 : 2;
  int n = n0 * 16 + (lane & 15);
  int kbase = k0 * 32 + (lane >> 4) * 8;
  short out[8];
#pragma unroll
  for (int j = 0; j < 8; ++j) {
    int k = kbase + j;
    int kk = k & 127, blk = k >> 7;
    float v;
    if (blk == 0)      v = Wself[rA * 16384 + kk * 128 + n] + Wself[rB * 16384 + kk * 128 + n];
    else if (blk == 1) v = Wneigh[rA * 16384 + kk * 128 + n];
    else               v = Wneigh[rB * 16384 + kk * 128 + n];
    out[j] = f2bf(v);
  }
  s16x4* dst = (s16x4*)&WTp[tid * 8];
  dst[0] = *(s16x4*)&out[0];
  dst[1] = *(s16x4*)&out[4];
}

__global__ __launch_bounds__(256) void prep_b_k(const float* __restrict__ b1,
                                                const float* __restrict__ b2,
                                                float* __restrict__ biasc) {
  int tid = blockIdx.x * 256 + threadIdx.x;
  if (tid >= 512) return;
  int l = tid >> 8, t = (tid >> 7) & 1, c = tid & 127;
  const float* b = l ? b2 : b1;
  int rA = t ? 0 : 1, rB = t ? 3 : 2;
  biasc[tid] = b[rA * 128 + c] + b[rB * 128 + c];
}

#define ACC8(u, a)                                            \
  {                                                           \
    _Pragma("unroll") for (int q = 0; q < 4; ++q) {           \
      union { unsigned w; float f; } lo_, hi_;                \
      lo_.w = (u)[q] << 16; hi_.w = (u)[q] & 0xffff0000u;     \
      (a)[2 * q] += lo_.f; (a)[2 * q + 1] += hi_.f;           \
    }                                                         \
  }

// One wave per node handling BOTH relations; both node types in one dispatch.
// Padded CSR (multiples of 8, zero-row tails) -> NO clamps, NO masks: every
// 8-edge batch is an unconditional {2 idx loads, 2 row loads, 2 ACC8}.
__global__ __launch_bounds__(256) void gather2_k(
    const unsigned* __restrict__ src0, const unsigned* __restrict__ src1,
    const int* __restrict__ csrp, const int* __restrict__ offp,
    const int* __restrict__ cnt,
    unsigned* __restrict__ m00, unsigned* __restrict__ m01,
    unsigned* __restrict__ m10, unsigned* __restrict__ m11) {
  int wv = __builtin_amdgcn_readfirstlane(threadIdx.x >> 6);
  int wid = blockIdx.x * 4 + wv;          // 0 .. 2*N_NODES-1
  int lane = threadIdx.x & 63;
  int type = wid >= N_NODES;
  int n = type ? wid - N_NODES : wid;
  const unsigned* src = type ? src1 : src0;
  int rA = type ? 0 : 1, rB = type ? 3 : 2;
  const int* csrA = csrp + (size_t)rA * PADCAP;
  const int* csrB = csrp + (size_t)rB * PADCAP;
  const int* offA = offp + rA * (N_NODES + 1);
  const int* offB = offp + rB * (N_NODES + 1);
  int degA = cnt[rA * N_NODES + n];
  int degB = cnt[rB * N_NODES + n];
  unsigned* mA = type ? m10 : m00;
  unsigned* mB = type ? m11 : m01;
  int pA0 = offA[n], pA1 = offA[n + 1];
  int pB0 = offB[n], pB1 = offB[n + 1];
  int rowg = lane >> 4;          // 0..3: row within each quad
  int colg = lane & 15;          // 16B slice: u32s colg*4 .. colg*4+3
  float a[8] = {}, b[8] = {};
  // first 8 edges of each relation: fully unconditional
  {
    int ia0 = csrA[pA0 + rowg], ia1 = csrA[pA0 + 4 + rowg];
    int ib0 = csrB[pB0 + rowg], ib1 = csrB[pB0 + 4 + rowg];
    u32x4 ua0 = *(const u32x4*)(src + (size_t)ia0 * 64 + colg * 4);
    u32x4 ua1 = *(const u32x4*)(src + (size_t)ia1 * 64 + colg * 4);
    u32x4 ub0 = *(const u32x4*)(src + (size_t)ib0 * 64 + colg * 4);
    u32x4 ub1 = *(const u32x4*)(src + (size_t)ib1 * 64 + colg * 4);
    ACC8(ua0, a); ACC8(ua1, a); ACC8(ub0, b); ACC8(ub1, b);
  }
  for (int p = pA0 + 8; p < pA1; p += 8) {
    int i0 = csrA[p + rowg], i1 = csrA[p + 4 + rowg];
    u32x4 u0 = *(const u32x4*)(src + (size_t)i0 * 64 + colg * 4);
    u32x4 u1 = *(const u32x4*)(src + (size_t)i1 * 64 + colg * 4);
    ACC8(u0, a); ACC8(u1, a);
  }
  for (int p = pB0 + 8; p < pB1; p += 8) {
    int i0 = csrB[p + rowg], i1 = csrB[p + 4 + rowg];
    u32x4 u0 = *(const u32x4*)(src + (size_t)i0 * 64 + colg * 4);
    u32x4 u1 = *(const u32x4*)(src + (size_t)i1 * 64 + colg * 4);
    ACC8(u0, b); ACC8(u1, b);
  }
#pragma unroll
  for (int q = 0; q < 8; ++q) {
    a[q] += __shfl_xor(a[q], 16); a[q] += __shfl_xor(a[q], 32);
    b[q] += __shfl_xor(b[q], 16); b[q] += __shfl_xor(b[q], 32);
  }
  if (rowg == 0) {
    float invA = 1.0f / (float)(degA > 1 ? degA : 1);
    float invB = 1.0f / (float)(degB > 1 ? degB : 1);
    u32x4 wa, wb;
#pragma unroll
    for (int q = 0; q < 4; ++q) {
      wa[q] = cvtpk(a[2 * q] * invA, a[2 * q + 1] * invA);
      wb[q] = cvtpk(b[2 * q] * invB, b[2 * q + 1] * invB);
    }
    *(u32x4*)(mA + (size_t)n * 64 + colg * 4) = wa;
    *(u32x4*)(mB + (size_t)n * 64 + colg * 4) = wb;
  }
}

// LDS-staged GEMM, 32KB LDS (3 chunks of 4 k-steps) -> 5 blocks/CU.
template<int OUT_RELU_BF16>
__global__ __launch_bounds__(256) void gemm2_k(
    const short* __restrict__ self0, const short* __restrict__ self1,
    const short* __restrict__ mA0, const short* __restrict__ mB0,
    const short* __restrict__ mA1, const short* __restrict__ mB1,
    const short* __restrict__ WTpL, const float* __restrict__ biascL,
    void* __restrict__ out0, void* __restrict__ out1) {
  __shared__ short Wlds[4 * 8 * 512];   // 32KB: 4 k-steps of B-fragments
  int type = blockIdx.y;
  const short* selfp = type ? self1 : self0;
  const short* meanA = type ? mA1 : mA0;
  const short* meanB = type ? mB1 : mB0;
  const short* WTp = WTpL + type * 49152;
  const float* biasc = biascL + type * 128;
  void* outp = type ? out1 : out0;
  int tid = threadIdx.x;
  int lane = tid & 63, wave = tid >> 6;
  int rowbase = blockIdx.x * 128 + wave * 32;
  int r0 = rowbase + (lane & 15), r1 = r0 + 16;
  int rc0 = r0 < N_NODES ? r0 : N_NODES - 1;
  int rc1 = r1 < N_NODES ? r1 : N_NODES - 1;
  int kg = lane >> 4;
  f32x4 acc[2][8] = {};
  for (int ch = 0; ch < 3; ++ch) {
    __syncthreads();
    const f32x4* s = (const f32x4*)WTp + ch * 2048;
    f32x4* dst = (f32x4*)Wlds;
#pragma unroll
    for (int i = 0; i < 8; ++i) dst[tid + i * 256] = s[tid + i * 256];
    __syncthreads();
    const short* mp = (ch == 0) ? selfp : ((ch == 1) ? meanA : meanB);
#pragma unroll
    for (int kh = 0; kh < 4; ++kh) {
      int kin = kh * 32 + kg * 8;
      bf16x8 a0 = *(const bf16x8*)(mp + (size_t)rc0 * 128 + kin);
      bf16x8 a1 = *(const bf16x8*)(mp + (size_t)rc1 * 128 + kin);
      const short* wb = &Wlds[kh * 4096 + lane * 8];
#pragma unroll
      for (int n0 = 0; n0 < 8; ++n0) {
        bf16x8 b = *(const bf16x8*)(wb + n0 * 512);
        acc[0][n0] = __builtin_amdgcn_mfma_f32_16x16x32_bf16(a0, b, acc[0][n0], 0, 0, 0);
        acc[1][n0] = __builtin_amdgcn_mfma_f32_16x16x32_bf16(a1, b, acc[1][n0], 0, 0, 0);
      }
    }
  }
  int colb = lane & 15, rloc = kg * 4;
#pragma unroll
  for (int mt = 0; mt < 2; ++mt) {
    int rb = rowbase + mt * 16 + rloc;
#pragma unroll
    for (int n0 = 0; n0 < 8; ++n0) {
      int cc = n0 * 16 + colb;
      float bv = biasc[cc];
#pragma unroll
      for (int j = 0; j < 4; ++j) {
        int rr = rb + j;
        if (rr < N_NODES) {
          float v = acc[mt][n0][j] + bv;
          if (OUT_RELU_BF16) {
            ((short*)outp)[(size_t)rr * 128 + cc] = f2bf(v > 0.f ? v : 0.f);
          } else {
            __builtin_nontemporal_store(v, (float*)outp + (size_t)rr * 128 + cc);
          }
        }
      }
    }
  }
}

extern "C" void kernel_launch(void* const* d_in, const int* in_sizes, int n_in,
                              void* d_out, int out_size, void* d_ws, size_t ws_size,
                              hipStream_t stream) {
  (void)in_sizes; (void)n_in; (void)out_size; (void)ws_size;
  const float* xq  = (const float*)d_in[0];
  const float* xp  = (const float*)d_in[1];
  const int*   src = (const int*)d_in[2];
  const int*   dst = (const int*)d_in[3];
  const float* Ws1 = (const float*)d_in[4];
  const float* Wn1 = (const float*)d_in[5];
  const float* b1  = (const float*)d_in[6];
  const float* Ws2 = (const float*)d_in[7];
  const float* Wn2 = (const float*)d_in[8];
  const float* b2  = (const float*)d_in[9];

  char* w = (char*)d_ws;
  int*   cnt    = (int*)w;      w += (size_t)4 * N_NODES * 4;
  int*   bincnt = (int*)w;      w += 4096;
  int*   offp   = (int*)w;      w += (size_t)4 * (N_NODES + 1) * 4;
  int*   csrp   = (int*)w;      w += (size_t)4 * PADCAP * 4;
  short* meanA  = (short*)w;    w += (size_t)N_NODES * 128 * 2;
  short* meanB  = (short*)w;    w += (size_t)N_NODES * 128 * 2;
  short* h1q    = (short*)w;    w += (size_t)(N_NODES + 1) * 128 * 2;
  short* h1p    = (short*)w;    w += (size_t)(N_NODES + 1) * 128 * 2;
  short* xqb    = (short*)w;    w += (size_t)(N_NODES + 1) * 128 * 2;
  short* xpb    = (short*)w;    w += (size_t)(N_NODES + 1) * 128 * 2;
  short* WTp    = (short*)w;    w += (size_t)4 * 49152 * 2;
  float* biasc  = (float*)w;    w += 512 * 4;
  int*   bsum   = (int*)w;      w += 4 * 128 * 4;
  // staging (packed u32) only live during CSR build, aliases meanA:
  unsigned* stage = (unsigned*)meanA;   // 4*196*3456*4B = 10.8MB <= 25.6MB
  // type-1 mean buffers alias dead storage (fully overwritten before read):
  unsigned* mL1C = (unsigned*)d_out;                 // L1: d_out is scratch
  unsigned* mL1D = mL1C + (size_t)N_NODES * 64;
  unsigned* mL2C = (unsigned*)xqb;                   // L2: xqb/xpb are dead
  unsigned* mL2D = (unsigned*)xpb;

  dim3 b256(256);
  const int bgrid = (NEDGE + 2047) / 2048;        // 293
  const int ggrid = (N_NODES + 127) / 128;        // 782
  const int wgrid = 2 * N_NODES / 4;              // 50000 (wave per node+type)
  const int cgrid = (N_NODES * 16 + 255) / 256;   // 6250
  const int ngrid = (N_NODES + 255) / 256;        // 391

  // --- CSR build via bucket counting-sort, PADDED to multiples of 8
  hipMemsetAsync(bincnt, 0, 4096, stream);
  // zero rows (index ZROW) for padded gather sources:
  hipMemsetAsync(xqb + (size_t)N_NODES * 128, 0, 256, stream);
  hipMemsetAsync(xpb + (size_t)N_NODES * 128, 0, 256, stream);
  hipMemsetAsync(h1q + (size_t)N_NODES * 128, 0, 256, stream);
  hipMemsetAsync(h1p + (size_t)N_NODES * 128, 0, 256, stream);
  bin_k<<<dim3(bgrid, 4), b256, 0, stream>>>(src, dst, bincnt, stage);
  hist_k<<<dim3(NBUCK, 4), b256, 0, stream>>>(stage, bincnt, cnt);
  scan1_k<<<dim3(NBLK, 4), b256, 0, stream>>>(cnt, bsum);
  scan2_k<<<dim3(1), dim3(128), 0, stream>>>(bsum);
  scan3_k<<<dim3(NBLK, 4), b256, 0, stream>>>(cnt, bsum, offp);
  place_k<<<dim3(NBUCK, 4), b256, 0, stream>>>(stage, bincnt, offp, csrp);
  padfill_k<<<dim3(ngrid, 4), b256, 0, stream>>>(cnt, offp, csrp);
  prep_w_k<<<dim3(384), b256, 0, stream>>>(Ws1, Wn1, Ws2, Wn2, WTp);
  prep_b_k<<<dim3(2), b256, 0, stream>>>(b1, b2, biasc);
  cvt2_k<<<dim3(cgrid, 2), b256, 0, stream>>>(xq, xp, (unsigned*)xqb, (unsigned*)xpb);

  // ---- Layer 1: one gather (both types), one gemm (both types)
  gather2_k<<<wgrid, b256, 0, stream>>>((const unsigned*)xpb, (const unsigned*)xqb,
      csrp, offp, cnt, (unsigned*)meanA, (unsigned*)meanB, mL1C, mL1D);
  gemm2_k<1><<<dim3(ggrid, 2), b256, 0, stream>>>(
      xqb, xpb, meanA, meanB, (const short*)mL1C, (const short*)mL1D,
      WTp, biasc, h1q, h1p);

  // ---- Layer 2
  gather2_k<<<wgrid, b256, 0, stream>>>((const unsigned*)h1p, (const unsigned*)h1q,
      csrp, offp, cnt, (unsigned*)meanA, (unsigned*)meanB, mL2C, mL2D);
  gemm2_k<0><<<dim3(ggrid, 2), b256, 0, stream>>>(
      h1q, h1p, meanA, meanB, (const short*)mL2C, (const short*)mL2D,
      WTp + 2 * 49152, biasc + 256,
      (float*)d_out, (float*)d_out + (size_t)N_NODES * 128);
}

// Round 13
// 468.981 us; speedup vs baseline: 1.0404x; 1.0404x over previous
//
#include <hip/hip_runtime.h>
#include <hip/hip_bf16.h>

#define N_NODES 100000
#define NEDGE   600000
#define SCAN_B  1024
#define NBLK    98            // ceil(N_NODES / SCAN_B)
#define BSHIFT  9             // bucket = dst >> 9 (512 nodes/bucket)
#define NBUCK   196           // ceil(N_NODES / 512)
#define BCAP    3456          // per (rel,bucket) staging cap (mean 3061 + 7 sigma)

typedef __attribute__((ext_vector_type(8))) short bf16x8;
typedef __attribute__((ext_vector_type(4))) short s16x4;
typedef __attribute__((ext_vector_type(4))) float f32x4;
typedef __attribute__((ext_vector_type(4))) unsigned u32x4;

__device__ __forceinline__ short f2bf(float f) {
  union { float f; unsigned u; } x; x.f = f;
  unsigned r = x.u + 0x7FFFu + ((x.u >> 16) & 1u);
  return (short)(r >> 16);
}

// packed bf16 convert: D = [bf16(lo), bf16(hi)] in one instruction (RNE)
__device__ __forceinline__ unsigned cvtpk(float lo, float hi) {
  unsigned r;
  asm("v_cvt_pk_bf16_f32 %0, %1, %2" : "=v"(r) : "v"(lo), "v"(hi));
  return r;
}

// Phase A: bin edges into 196 per-bucket segments. Packed entry:
// bits 0..16 = src (max 99999 < 2^17), bits 17..25 = dst & 511.
__global__ __launch_bounds__(256) void bin_k(const int* __restrict__ sidx,
                                             const int* __restrict__ didx,
                                             int* __restrict__ bincnt,
                                             unsigned* __restrict__ stage) {
  __shared__ int hist[NBUCK];
  __shared__ int base[NBUCK];
  int r = blockIdx.y, t = threadIdx.x;
  int e0 = blockIdx.x * 2048 + t;
  const int* dd = didx + (size_t)r * NEDGE;
  const int* ss = sidx + (size_t)r * NEDGE;
  for (int i = t; i < NBUCK; i += 256) hist[i] = 0;
  __syncthreads();
  unsigned pv[8]; int bu[8], lr[8];
#pragma unroll
  for (int j = 0; j < 8; ++j) {
    int e = e0 + j * 256;
    if (e < NEDGE) {
      int dv = dd[e];
      bu[j] = dv >> BSHIFT;
      pv[j] = (unsigned)ss[e] | ((unsigned)(dv & 511) << 17);
      lr[j] = atomicAdd(&hist[bu[j]], 1);     // LDS atomic
    }
  }
  __syncthreads();
  for (int i = t; i < NBUCK; i += 256)
    base[i] = atomicAdd(&bincnt[r * NBUCK + i], hist[i]);
  __syncthreads();
#pragma unroll
  for (int j = 0; j < 8; ++j) {
    int e = e0 + j * 256;
    if (e < NEDGE)
      stage[(size_t)(r * NBUCK + bu[j]) * BCAP + base[bu[j]] + lr[j]] = pv[j];
  }
}

// Phase B: one block per (bucket, rel): LDS histogram, coalesced cnt write.
__global__ __launch_bounds__(256) void hist_k(const unsigned* __restrict__ stage,
                                              const int* __restrict__ bincnt,
                                              int* __restrict__ cnt) {
  __shared__ int h[512];
  int bu = blockIdx.x, r = blockIdx.y, t = threadIdx.x;
  int len = bincnt[r * NBUCK + bu];
  const unsigned* sg = stage + (size_t)(r * NBUCK + bu) * BCAP;
  h[t] = 0; h[t + 256] = 0;
  __syncthreads();
  for (int i = t; i < len; i += 256) atomicAdd(&h[sg[i] >> 17], 1);  // LDS
  __syncthreads();
  int lo = bu << BSHIFT;
  int d0 = lo + t;
  if (d0 < N_NODES)       cnt[r * N_NODES + d0]       = h[t];
  if (d0 + 256 < N_NODES) cnt[r * N_NODES + d0 + 256] = h[t + 256];
}

__global__ __launch_bounds__(256) void scan1_k(const int* __restrict__ cnt,
                                               int* __restrict__ bsum) {
  __shared__ int lds[256];
  int b = blockIdx.x, r = blockIdx.y, t = threadIdx.x;
  int i0 = b * SCAN_B + t * 4;
  int s = 0;
#pragma unroll
  for (int j = 0; j < 4; ++j)
    if (i0 + j < N_NODES) s += cnt[r * N_NODES + i0 + j];
  lds[t] = s;
  __syncthreads();
  for (int st = 128; st > 0; st >>= 1) {
    if (t < st) lds[t] += lds[t + st];
    __syncthreads();
  }
  if (t == 0) bsum[r * NBLK + b] = lds[0];
}

__global__ __launch_bounds__(128) void scan2_k(int* __restrict__ bsum) {
  __shared__ int buf[128];
  int t = threadIdx.x;
  for (int r = 0; r < 4; ++r) {
    int v = (t < NBLK) ? bsum[r * NBLK + t] : 0;
    buf[t] = v;
    __syncthreads();
    for (int st = 1; st < 128; st <<= 1) {
      int x = (t >= st) ? buf[t - st] : 0;
      __syncthreads();
      buf[t] += x;
      __syncthreads();
    }
    if (t < NBLK) bsum[r * NBLK + t] = buf[t] - v;   // exclusive
    __syncthreads();
  }
}

__global__ __launch_bounds__(256) void scan3_k(const int* __restrict__ cnt,
                                               const int* __restrict__ bsum,
                                               int* __restrict__ off) {
  __shared__ int lds[256];
  int b = blockIdx.x, r = blockIdx.y, t = threadIdx.x;
  int i0 = b * SCAN_B + t * 4;
  int c[4] = {0, 0, 0, 0};
#pragma unroll
  for (int j = 0; j < 4; ++j)
    if (i0 + j < N_NODES) c[j] = cnt[r * N_NODES + i0 + j];
  int s = c[0] + c[1] + c[2] + c[3];
  lds[t] = s;
  __syncthreads();
  for (int st = 1; st < 256; st <<= 1) {
    int x = (t >= st) ? lds[t - st] : 0;
    __syncthreads();
    lds[t] += x;
    __syncthreads();
  }
  int run = bsum[r * NBLK + b] + lds[t] - s;
  int* o = off + r * (N_NODES + 1);
#pragma unroll
  for (int j = 0; j < 4; ++j) {
    if (i0 + j < N_NODES) { o[i0 + j] = run; run += c[j]; }
  }
  if (b == 0 && t == 0) o[N_NODES] = NEDGE;
}

// Phase C: one block per (bucket, rel): place edges with LDS-only cursors.
__global__ __launch_bounds__(256) void place_k(const unsigned* __restrict__ stage,
                                               const int* __restrict__ bincnt,
                                               const int* __restrict__ off,
                                               int* __restrict__ csr) {
  __shared__ int ofl[512];
  __shared__ int cur[512];
  int bu = blockIdx.x, r = blockIdx.y, t = threadIdx.x;
  int len = bincnt[r * NBUCK + bu];
  const unsigned* sg = stage + (size_t)(r * NBUCK + bu) * BCAP;
  const int* of = off + r * (N_NODES + 1);
  int* cs = csr + (size_t)r * NEDGE;
  int lo = bu << BSHIFT;
  int d0 = lo + t;
  ofl[t]       = (d0 < N_NODES) ? of[d0] : 0;
  ofl[t + 256] = (d0 + 256 < N_NODES) ? of[d0 + 256] : 0;
  cur[t] = 0; cur[t + 256] = 0;
  __syncthreads();
  for (int i = t; i < len; i += 256) {
    unsigned v = sg[i];
    int dl = v >> 17;
    int pos = ofl[dl] + atomicAdd(&cur[dl], 1);   // LDS atomic
    cs[pos] = (int)(v & 0x1FFFFu);
  }
}

// f32 -> packed bf16 for both inputs in one dispatch (blockIdx.y selects).
__global__ __launch_bounds__(256) void cvt2_k(const float* __restrict__ x0,
                                              const float* __restrict__ x1,
                                              unsigned* __restrict__ o0,
                                              unsigned* __restrict__ o1) {
  const float* x = blockIdx.y ? x1 : x0;
  unsigned* o = blockIdx.y ? o1 : o0;
  int i = blockIdx.x * 256 + threadIdx.x;     // i < N_NODES*16
  if (i >= N_NODES * 16) return;
  f32x4 v0 = ((const f32x4*)x)[i * 2];
  f32x4 v1 = ((const f32x4*)x)[i * 2 + 1];
  ((u32x4*)o)[i] = (u32x4){cvtpk(v0[0], v0[1]), cvtpk(v0[2], v0[3]),
                           cvtpk(v1[0], v1[1]), cvtpk(v1[2], v1[3])};
}

// Pack combined weights into MFMA B-fragment-linear layout.
__global__ __launch_bounds__(256) void prep_w_k(const float* __restrict__ Ws1,
                                                const float* __restrict__ Wn1,
                                                const float* __restrict__ Ws2,
                                                const float* __restrict__ Wn2,
                                                short* __restrict__ WTp) {
  int tid = blockIdx.x * 256 + threadIdx.x;  // 0..98303
  int lane = tid & 63;
  int n0 = (tid >> 6) & 7;
  int idx3 = tid >> 9;
  int k0 = idx3 % 12;
  int lt = idx3 / 12;
  int l = lt >> 1, t = lt & 1;
  const float* Wself  = l ? Ws2 : Ws1;
  const float* Wneigh = l ? Wn2 : Wn1;
  int rA = t ? 0 : 1, rB = t ? 3 : 2;
  int n = n0 * 16 + (lane & 15);
  int kbase = k0 * 32 + (lane >> 4) * 8;
  short out[8];
#pragma unroll
  for (int j = 0; j < 8; ++j) {
    int k = kbase + j;
    int kk = k & 127, blk = k >> 7;
    float v;
    if (blk == 0)      v = Wself[rA * 16384 + kk * 128 + n] + Wself[rB * 16384 + kk * 128 + n];
    else if (blk == 1) v = Wneigh[rA * 16384 + kk * 128 + n];
    else               v = Wneigh[rB * 16384 + kk * 128 + n];
    out[j] = f2bf(v);
  }
  s16x4* dst = (s16x4*)&WTp[tid * 8];
  dst[0] = *(s16x4*)&out[0];
  dst[1] = *(s16x4*)&out[4];
}

__global__ __launch_bounds__(256) void prep_b_k(const float* __restrict__ b1,
                                                const float* __restrict__ b2,
                                                float* __restrict__ biasc) {
  int tid = blockIdx.x * 256 + threadIdx.x;
  if (tid >= 512) return;
  int l = tid >> 8, t = (tid >> 7) & 1, c = tid & 127;
  const float* b = l ? b2 : b1;
  int rA = t ? 0 : 1, rB = t ? 3 : 2;
  biasc[tid] = b[rA * 128 + c] + b[rB * 128 + c];
}

#define ACC8(u, a)                                            \
  {                                                           \
    _Pragma("unroll") for (int q = 0; q < 4; ++q) {           \
      union { unsigned w; float f; } lo_, hi_;                \
      lo_.w = (u)[q] << 16; hi_.w = (u)[q] & 0xffff0000u;     \
      (a)[2 * q] += lo_.f; (a)[2 * q + 1] += hi_.f;           \
    }                                                         \
  }

__device__ __forceinline__ int clampi(int q, int p0, int p1) {
  int t = q < p1 ? q : p0;
  return t < NEDGE ? t : 0;
}

// One wave per node handling BOTH relations; both node types in one dispatch.
__global__ __launch_bounds__(256) void gather2_k(
    const unsigned* __restrict__ src0, const unsigned* __restrict__ src1,
    const int* __restrict__ csr, const int* __restrict__ off,
    unsigned* __restrict__ m00, unsigned* __restrict__ m01,
    unsigned* __restrict__ m10, unsigned* __restrict__ m11) {
  int wv = __builtin_amdgcn_readfirstlane(threadIdx.x >> 6);
  int wid = blockIdx.x * 4 + wv;          // 0 .. 2*N_NODES-1
  int lane = threadIdx.x & 63;
  int type = wid >= N_NODES;
  int n = type ? wid - N_NODES : wid;
  const unsigned* src = type ? src1 : src0;
  const int* csrA = csr + (type ? 0 : 1) * NEDGE;
  const int* csrB = csr + (type ? 3 : 2) * NEDGE;
  const int* offA = off + (type ? 0 : 1) * (N_NODES + 1);
  const int* offB = off + (type ? 3 : 2) * (N_NODES + 1);
  unsigned* mA = type ? m10 : m00;
  unsigned* mB = type ? m11 : m01;
  int pA0 = offA[n], pA1 = offA[n + 1];
  int pB0 = offB[n], pB1 = offB[n + 1];
  int degA = pA1 - pA0, degB = pB1 - pB0;
  int rowg = lane >> 4;          // 0..3: row within each quad
  int colg = lane & 15;          // 16B slice: u32s colg*4 .. colg*4+3
  float a[8] = {}, b[8] = {};
  // fast path: first 8 edges of each relation, all loads issued up front
  {
    int ia0 = csrA[clampi(pA0 + rowg,     pA0, pA1)];
    int ia1 = csrA[clampi(pA0 + 4 + rowg, pA0, pA1)];
    int ib0 = csrB[clampi(pB0 + rowg,     pB0, pB1)];
    int ib1 = csrB[clampi(pB0 + 4 + rowg, pB0, pB1)];
    u32x4 ua0 = *(const u32x4*)(src + (size_t)ia0 * 64 + colg * 4);
    u32x4 ua1 = *(const u32x4*)(src + (size_t)ia1 * 64 + colg * 4);
    u32x4 ub0 = *(const u32x4*)(src + (size_t)ib0 * 64 + colg * 4);
    u32x4 ub1 = *(const u32x4*)(src + (size_t)ib1 * 64 + colg * 4);
    if (pA0 + rowg     < pA1) ACC8(ua0, a);
    if (pA0 + 4 + rowg < pA1) ACC8(ua1, a);
    if (pB0 + rowg     < pB1) ACC8(ub0, b);
    if (pB0 + 4 + rowg < pB1) ACC8(ub1, b);
  }
  for (int p = pA0 + 8; p < pA1; p += 8) {
    int i0 = csrA[clampi(p + rowg,     pA0, pA1)];
    int i1 = csrA[clampi(p + 4 + rowg, pA0, pA1)];
    u32x4 u0 = *(const u32x4*)(src + (size_t)i0 * 64 + colg * 4);
    u32x4 u1 = *(const u32x4*)(src + (size_t)i1 * 64 + colg * 4);
    if (p + rowg     < pA1) ACC8(u0, a);
    if (p + 4 + rowg < pA1) ACC8(u1, a);
  }
  for (int p = pB0 + 8; p < pB1; p += 8) {
    int i0 = csrB[clampi(p + rowg,     pB0, pB1)];
    int i1 = csrB[clampi(p + 4 + rowg, pB0, pB1)];
    u32x4 u0 = *(const u32x4*)(src + (size_t)i0 * 64 + colg * 4);
    u32x4 u1 = *(const u32x4*)(src + (size_t)i1 * 64 + colg * 4);
    if (p + rowg     < pB1) ACC8(u0, b);
    if (p + 4 + rowg < pB1) ACC8(u1, b);
  }
#pragma unroll
  for (int q = 0; q < 8; ++q) {
    a[q] += __shfl_xor(a[q], 16); a[q] += __shfl_xor(a[q], 32);
    b[q] += __shfl_xor(b[q], 16); b[q] += __shfl_xor(b[q], 32);
  }
  if (rowg == 0) {
    float invA = 1.0f / (float)(degA > 1 ? degA : 1);
    float invB = 1.0f / (float)(degB > 1 ? degB : 1);
    u32x4 wa, wb;
#pragma unroll
    for (int q = 0; q < 4; ++q) {
      wa[q] = cvtpk(a[2 * q] * invA, a[2 * q + 1] * invA);
      wb[q] = cvtpk(b[2 * q] * invB, b[2 * q + 1] * invB);
    }
    *(u32x4*)(mA + (size_t)n * 64 + colg * 4) = wa;
    *(u32x4*)(mB + (size_t)n * 64 + colg * 4) = wb;
  }
}

// LDS-staged GEMM with T14 issue-early/write-late double-buffer:
// 6 chunks of 2 k-steps (16KB each), 2 LDS buffers (32KB total).
// Next chunk's W loads issue BEFORE the MFMA block (latency hides under
// 32 MFMAs/wave), regs written to the other buffer after, 1 barrier/chunk.
template<int OUT_RELU_BF16>
__global__ __launch_bounds__(256) void gemm2_k(
    const short* __restrict__ self0, const short* __restrict__ self1,
    const short* __restrict__ mA0, const short* __restrict__ mB0,
    const short* __restrict__ mA1, const short* __restrict__ mB1,
    const short* __restrict__ WTpL, const float* __restrict__ biascL,
    void* __restrict__ out0, void* __restrict__ out1) {
  __shared__ short Wlds[2][8192];   // 2 x 16KB (2 k-steps each)
  int type = blockIdx.y;
  const short* selfp = type ? self1 : self0;
  const short* meanA = type ? mA1 : mA0;
  const short* meanB = type ? mB1 : mB0;
  const short* WTp = WTpL + type * 49152;
  const float* biasc = biascL + type * 128;
  void* outp = type ? out1 : out0;
  int tid = threadIdx.x;
  int lane = tid & 63, wave = tid >> 6;
  int rowbase = blockIdx.x * 128 + wave * 32;
  int r0 = rowbase + (lane & 15), r1 = r0 + 16;
  int rc0 = r0 < N_NODES ? r0 : N_NODES - 1;
  int rc1 = r1 < N_NODES ? r1 : N_NODES - 1;
  int kg = lane >> 4;
  f32x4 acc[2][8] = {};
  const f32x4* Wsrc = (const f32x4*)WTp;   // 6 chunks x 1024 f32x4
  f32x4 st[4];
  // prologue: stage chunk 0
#pragma unroll
  for (int j = 0; j < 4; ++j) st[j] = Wsrc[tid + j * 256];
  {
    f32x4* d = (f32x4*)Wlds[0];
#pragma unroll
    for (int j = 0; j < 4; ++j) d[tid + j * 256] = st[j];
  }
  __syncthreads();
  for (int c = 0; c < 6; ++c) {
    if (c < 5) {
#pragma unroll
      for (int j = 0; j < 4; ++j) st[j] = Wsrc[(c + 1) * 1024 + tid + j * 256];
    }
    const short* mp = (c < 2) ? selfp : ((c < 4) ? meanA : meanB);
    const short* wbase = Wlds[c & 1];
#pragma unroll
    for (int kh = 0; kh < 2; ++kh) {
      int kk = (c * 2 + kh) & 3;           // k-step within mp's 128-col block
      int kin = kk * 32 + kg * 8;
      bf16x8 a0 = *(const bf16x8*)(mp + (size_t)rc0 * 128 + kin);
      bf16x8 a1 = *(const bf16x8*)(mp + (size_t)rc1 * 128 + kin);
      const short* wb = wbase + kh * 4096 + lane * 8;
#pragma unroll
      for (int n0 = 0; n0 < 8; ++n0) {
        bf16x8 b = *(const bf16x8*)(wb + n0 * 512);
        acc[0][n0] = __builtin_amdgcn_mfma_f32_16x16x32_bf16(a0, b, acc[0][n0], 0, 0, 0);
        acc[1][n0] = __builtin_amdgcn_mfma_f32_16x16x32_bf16(a1, b, acc[1][n0], 0, 0, 0);
      }
    }
    if (c < 5) {
      f32x4* d = (f32x4*)Wlds[(c + 1) & 1];
#pragma unroll
      for (int j = 0; j < 4; ++j) d[tid + j * 256] = st[j];
    }
    __syncthreads();
  }
  int colb = lane & 15, rloc = kg * 4;
#pragma unroll
  for (int mt = 0; mt < 2; ++mt) {
    int rb = rowbase + mt * 16 + rloc;
#pragma unroll
    for (int n0 = 0; n0 < 8; ++n0) {
      int cc = n0 * 16 + colb;
      float bv = biasc[cc];
#pragma unroll
      for (int j = 0; j < 4; ++j) {
        int rr = rb + j;
        if (rr < N_NODES) {
          float v = acc[mt][n0][j] + bv;
          if (OUT_RELU_BF16) {
            ((short*)outp)[(size_t)rr * 128 + cc] = f2bf(v > 0.f ? v : 0.f);
          } else {
            __builtin_nontemporal_store(v, (float*)outp + (size_t)rr * 128 + cc);
          }
        }
      }
    }
  }
}

extern "C" void kernel_launch(void* const* d_in, const int* in_sizes, int n_in,
                              void* d_out, int out_size, void* d_ws, size_t ws_size,
                              hipStream_t stream) {
  (void)in_sizes; (void)n_in; (void)out_size; (void)ws_size;
  const float* xq  = (const float*)d_in[0];
  const float* xp  = (const float*)d_in[1];
  const int*   src = (const int*)d_in[2];
  const int*   dst = (const int*)d_in[3];
  const float* Ws1 = (const float*)d_in[4];
  const float* Wn1 = (const float*)d_in[5];
  const float* b1  = (const float*)d_in[6];
  const float* Ws2 = (const float*)d_in[7];
  const float* Wn2 = (const float*)d_in[8];
  const float* b2  = (const float*)d_in[9];

  char* w = (char*)d_ws;
  int*   cnt    = (int*)w;      w += (size_t)4 * N_NODES * 4;
  int*   bincnt = (int*)w;      w += 4096;
  int*   off    = (int*)w;      w += (size_t)4 * (N_NODES + 1) * 4;
  int*   csr    = (int*)w;      w += (size_t)4 * NEDGE * 4;
  short* meanA  = (short*)w;    w += (size_t)N_NODES * 128 * 2;
  short* meanB  = (short*)w;    w += (size_t)N_NODES * 128 * 2;
  short* h1q    = (short*)w;    w += (size_t)N_NODES * 128 * 2;
  short* h1p    = (short*)w;    w += (size_t)N_NODES * 128 * 2;
  short* xqb    = (short*)w;    w += (size_t)N_NODES * 128 * 2;
  short* xpb    = (short*)w;    w += (size_t)N_NODES * 128 * 2;
  short* WTp    = (short*)w;    w += (size_t)4 * 49152 * 2;
  float* biasc  = (float*)w;    w += 512 * 4;
  int*   bsum   = (int*)w;      w += 4 * 128 * 4;
  // staging (packed u32) only live during CSR build, aliases meanA:
  unsigned* stage = (unsigned*)meanA;   // 4*196*3456*4B = 10.8MB <= 25.6MB
  // type-1 mean buffers alias dead storage (fully overwritten before read):
  unsigned* mL1C = (unsigned*)d_out;                 // L1: d_out is scratch
  unsigned* mL1D = mL1C + (size_t)N_NODES * 64;
  unsigned* mL2C = (unsigned*)xqb;                   // L2: xqb/xpb are dead
  unsigned* mL2D = (unsigned*)xpb;

  dim3 b256(256);
  const int bgrid = (NEDGE + 2047) / 2048;        // 293
  const int ggrid = (N_NODES + 127) / 128;        // 782
  const int wgrid = 2 * N_NODES / 4;              // 50000 (wave per node+type)
  const int cgrid = (N_NODES * 16 + 255) / 256;   // 6250

  // --- CSR build via bucket counting-sort (no per-edge global atomics)
  hipMemsetAsync(bincnt, 0, 4096, stream);
  bin_k<<<dim3(bgrid, 4), b256, 0, stream>>>(src, dst, bincnt, stage);
  hist_k<<<dim3(NBUCK, 4), b256, 0, stream>>>(stage, bincnt, cnt);
  scan1_k<<<dim3(NBLK, 4), b256, 0, stream>>>(cnt, bsum);
  scan2_k<<<dim3(1), dim3(128), 0, stream>>>(bsum);
  scan3_k<<<dim3(NBLK, 4), b256, 0, stream>>>(cnt, bsum, off);
  place_k<<<dim3(NBUCK, 4), b256, 0, stream>>>(stage, bincnt, off, csr);
  prep_w_k<<<dim3(384), b256, 0, stream>>>(Ws1, Wn1, Ws2, Wn2, WTp);
  prep_b_k<<<dim3(2), b256, 0, stream>>>(b1, b2, biasc);
  cvt2_k<<<dim3(cgrid, 2), b256, 0, stream>>>(xq, xp, (unsigned*)xqb, (unsigned*)xpb);

  // ---- Layer 1: one gather (both types), one gemm (both types)
  gather2_k<<<wgrid, b256, 0, stream>>>((const unsigned*)xpb, (const unsigned*)xqb,
      csr, off, (unsigned*)meanA, (unsigned*)meanB, mL1C, mL1D);
  gemm2_k<1><<<dim3(ggrid, 2), b256, 0, stream>>>(
      xqb, xpb, meanA, meanB, (const short*)mL1C, (const short*)mL1D,
      WTp, biasc, h1q, h1p);

  // ---- Layer 2
  gather2_k<<<wgrid, b256, 0, stream>>>((const unsigned*)h1p, (const unsigned*)h1q,
      csr, off, (unsigned*)meanA, (unsigned*)meanB, mL2C, mL2D);
  gemm2_k<0><<<dim3(ggrid, 2), b256, 0, stream>>>(
      h1q, h1p, meanA, meanB, (const short*)mL2C, (const short*)mL2D,
      WTp + 2 * 49152, biasc + 256,
      (float*)d_out, (float*)d_out + (size_t)N_NODES * 128);
}

// Round 15
// 461.624 us; speedup vs baseline: 1.0569x; 1.0159x over previous
//
#include <hip/hip_runtime.h>
#include <hip/hip_bf16.h>

#define N_NODES 100000
#define NEDGE   600000
#define BSHIFT  9             // bucket = dst >> 9 (512 nodes/bucket)
#define NBUCK   196           // ceil(N_NODES / 512)
#define BCAP    3456          // per (rel,bucket) staging cap (mean 3061 + 7 sigma)
#define CGRID   6250          // N_NODES*16/256 (cvt blocks per type)
#define WGRID   96            // weight-pack blocks: 24576 tids * 8 shorts = 196608

typedef __attribute__((ext_vector_type(8))) short bf16x8;
typedef __attribute__((ext_vector_type(4))) short s16x4;
typedef __attribute__((ext_vector_type(4))) float f32x4;
typedef __attribute__((ext_vector_type(4))) unsigned u32x4;

__device__ __forceinline__ short f2bf(float f) {
  union { float f; unsigned u; } x; x.f = f;
  unsigned r = x.u + 0x7FFFu + ((x.u >> 16) & 1u);
  return (short)(r >> 16);
}

// packed bf16 convert: D = [bf16(lo), bf16(hi)] in one instruction (RNE)
__device__ __forceinline__ unsigned cvtpk(float lo, float hi) {
  unsigned r;
  asm("v_cvt_pk_bf16_f32 %0, %1, %2" : "=v"(r) : "v"(lo), "v"(hi));
  return r;
}

// Phase A: bin edges into 196 per-bucket segments. Packed entry:
// bits 0..16 = src (max 99999 < 2^17), bits 17..25 = dst & 511.
__global__ __launch_bounds__(256) void bin_k(const int* __restrict__ sidx,
                                             const int* __restrict__ didx,
                                             int* __restrict__ bincnt,
                                             unsigned* __restrict__ stage) {
  __shared__ int hist[NBUCK];
  __shared__ int base[NBUCK];
  int r = blockIdx.y, t = threadIdx.x;
  int e0 = blockIdx.x * 2048 + t;
  const int* dd = didx + (size_t)r * NEDGE;
  const int* ss = sidx + (size_t)r * NEDGE;
  for (int i = t; i < NBUCK; i += 256) hist[i] = 0;
  __syncthreads();
  unsigned pv[8]; int bu[8], lr[8];
#pragma unroll
  for (int j = 0; j < 8; ++j) {
    int e = e0 + j * 256;
    if (e < NEDGE) {
      int dv = dd[e];
      bu[j] = dv >> BSHIFT;
      pv[j] = (unsigned)ss[e] | ((unsigned)(dv & 511) << 17);
      lr[j] = atomicAdd(&hist[bu[j]], 1);     // LDS atomic
    }
  }
  __syncthreads();
  for (int i = t; i < NBUCK; i += 256)
    base[i] = atomicAdd(&bincnt[r * NBUCK + i], hist[i]);
  __syncthreads();
#pragma unroll
  for (int j = 0; j < 8; ++j) {
    int e = e0 + j * 256;
    if (e < NEDGE)
      stage[(size_t)(r * NBUCK + bu[j]) * BCAP + base[bu[j]] + lr[j]] = pv[j];
  }
}

// Phase B: one block per (bucket, rel): LDS histogram -> cnt (coalesced)
// AND bucket total -> bucketsum (replaces the old global scan1 pass).
__global__ __launch_bounds__(256) void hist_k(const unsigned* __restrict__ stage,
                                              const int* __restrict__ bincnt,
                                              int* __restrict__ cnt,
                                              int* __restrict__ bucketsum) {
  __shared__ int h[512];
  __shared__ int red[256];
  int bu = blockIdx.x, r = blockIdx.y, t = threadIdx.x;
  int len = bincnt[r * NBUCK + bu];
  const unsigned* sg = stage + (size_t)(r * NBUCK + bu) * BCAP;
  h[t] = 0; h[t + 256] = 0;
  __syncthreads();
  for (int i = t; i < len; i += 256) atomicAdd(&h[sg[i] >> 17], 1);  // LDS
  __syncthreads();
  int lo = bu << BSHIFT;
  int d0 = lo + t;
  if (d0 < N_NODES)       cnt[r * N_NODES + d0]       = h[t];
  if (d0 + 256 < N_NODES) cnt[r * N_NODES + d0 + 256] = h[t + 256];
  red[t] = h[t] + h[t + 256];
  __syncthreads();
  for (int st = 128; st > 0; st >>= 1) {
    if (t < st) red[t] += red[t + st];
    __syncthreads();
  }
  if (t == 0) bucketsum[r * NBUCK + bu] = red[0];
}

// exclusive scan of the 196 bucket sums per relation. 1 block, 256 thr.
__global__ __launch_bounds__(256) void scan2_k(int* __restrict__ bucketsum) {
  __shared__ int buf[256];
  int t = threadIdx.x;
  for (int r = 0; r < 4; ++r) {
    int v = (t < NBUCK) ? bucketsum[r * NBUCK + t] : 0;
    buf[t] = v;
    __syncthreads();
    for (int st = 1; st < 256; st <<= 1) {
      int x = (t >= st) ? buf[t - st] : 0;
      __syncthreads();
      buf[t] += x;
      __syncthreads();
    }
    if (t < NBUCK) bucketsum[r * NBUCK + t] = buf[t] - v;   // exclusive
    __syncthreads();
  }
}

// bucket-local exclusive scan: one block per (bucket, rel), 512 counts.
__global__ __launch_bounds__(256) void scan3_k(const int* __restrict__ cnt,
                                               const int* __restrict__ bucketsum,
                                               int* __restrict__ off) {
  __shared__ int ps[256];
  int bu = blockIdx.x, r = blockIdx.y, t = threadIdx.x;
  int lo = bu << BSHIFT;
  int i0 = lo + 2 * t;
  int c0 = (i0 < N_NODES) ? cnt[r * N_NODES + i0] : 0;
  int c1 = (i0 + 1 < N_NODES) ? cnt[r * N_NODES + i0 + 1] : 0;
  int pair = c0 + c1;
  ps[t] = pair;
  __syncthreads();
  for (int st = 1; st < 256; st <<= 1) {
    int x = (t >= st) ? ps[t - st] : 0;
    __syncthreads();
    ps[t] += x;
    __syncthreads();
  }
  int base = bucketsum[r * NBUCK + bu] + ps[t] - pair;
  int* o = off + r * (N_NODES + 1);
  if (i0 < N_NODES)     o[i0]     = base;
  if (i0 + 1 < N_NODES) o[i0 + 1] = base + c0;
  if (bu == 0 && t == 0) o[N_NODES] = NEDGE;
}

// Phase C: one block per (bucket, rel): place edges with LDS-only cursors.
__global__ __launch_bounds__(256) void place_k(const unsigned* __restrict__ stage,
                                               const int* __restrict__ bincnt,
                                               const int* __restrict__ off,
                                               int* __restrict__ csr) {
  __shared__ int ofl[512];
  __shared__ int cur[512];
  int bu = blockIdx.x, r = blockIdx.y, t = threadIdx.x;
  int len = bincnt[r * NBUCK + bu];
  const unsigned* sg = stage + (size_t)(r * NBUCK + bu) * BCAP;
  const int* of = off + r * (N_NODES + 1);
  int* cs = csr + (size_t)r * NEDGE;
  int lo = bu << BSHIFT;
  int d0 = lo + t;
  ofl[t]       = (d0 < N_NODES) ? of[d0] : 0;
  ofl[t + 256] = (d0 + 256 < N_NODES) ? of[d0 + 256] : 0;
  cur[t] = 0; cur[t + 256] = 0;
  __syncthreads();
  for (int i = t; i < len; i += 256) {
    unsigned v = sg[i];
    int dl = v >> 17;
    int pos = ofl[dl] + atomicAdd(&cur[dl], 1);   // LDS atomic
    cs[pos] = (int)(v & 0x1FFFFu);
  }
}

// Fat prep: cvt(xq), cvt(xp), prep_w, prep_b in ONE dispatch (blockIdx ranges).
// Weight section is exactly WGRID=96 blocks (24576 tids): full coverage of
// 4 x 49152 shorts with ZERO out-of-bounds writes (the old 384-block grid
// wrote 4x past WTp — latent since r0, exposed by fusing prep_b in r14).
__global__ __launch_bounds__(256) void fatprep_k(
    const float* __restrict__ xq, const float* __restrict__ xp,
    unsigned* __restrict__ xqb, unsigned* __restrict__ xpb,
    const float* __restrict__ Ws1, const float* __restrict__ Wn1,
    const float* __restrict__ Ws2, const float* __restrict__ Wn2,
    short* __restrict__ WTp,
    const float* __restrict__ b1, const float* __restrict__ b2,
    float* __restrict__ biasc) {
  int b = blockIdx.x, t = threadIdx.x;
  if (b < 2 * CGRID) {
    // f32 -> packed bf16
    const float* x = (b < CGRID) ? xq : xp;
    unsigned* o = (b < CGRID) ? xqb : xpb;
    int i = (b < CGRID ? b : b - CGRID) * 256 + t;
    f32x4 v0 = ((const f32x4*)x)[i * 2];
    f32x4 v1 = ((const f32x4*)x)[i * 2 + 1];
    ((u32x4*)o)[i] = (u32x4){cvtpk(v0[0], v0[1]), cvtpk(v0[2], v0[3]),
                             cvtpk(v1[0], v1[1]), cvtpk(v1[2], v1[3])};
  } else if (b < 2 * CGRID + WGRID) {
    // pack combined weights into MFMA B-fragment-linear layout
    int tid = (b - 2 * CGRID) * 256 + t;  // 0..24575
    int lane = tid & 63;
    int n0 = (tid >> 6) & 7;
    int idx3 = tid >> 9;                  // 0..47 = lt*12 + k0
    int k0 = idx3 % 12;
    int lt = idx3 / 12;                   // 0..3
    int l = lt >> 1, ty = lt & 1;
    const float* Wself  = l ? Ws2 : Ws1;
    const float* Wneigh = l ? Wn2 : Wn1;
    int rA = ty ? 0 : 1, rB = ty ? 3 : 2;
    int n = n0 * 16 + (lane & 15);
    int kbase = k0 * 32 + (lane >> 4) * 8;
    short out[8];
#pragma unroll
    for (int j = 0; j < 8; ++j) {
      int k = kbase + j;
      int kk = k & 127, blk = k >> 7;
      float v;
      if (blk == 0)      v = Wself[rA * 16384 + kk * 128 + n] + Wself[rB * 16384 + kk * 128 + n];
      else if (blk == 1) v = Wneigh[rA * 16384 + kk * 128 + n];
      else               v = Wneigh[rB * 16384 + kk * 128 + n];
      out[j] = f2bf(v);
    }
    s16x4* dst = (s16x4*)&WTp[tid * 8];
    dst[0] = *(s16x4*)&out[0];
    dst[1] = *(s16x4*)&out[4];
  } else {
    // bias combine: 512 items with 256 threads (2 each)
#pragma unroll
    for (int q = 0; q < 2; ++q) {
      int tid = t + q * 256;
      int l = tid >> 8, ty = (tid >> 7) & 1, c = tid & 127;
      const float* bb = l ? b2 : b1;
      int rA = ty ? 0 : 1, rB = ty ? 3 : 2;
      biasc[tid] = bb[rA * 128 + c] + bb[rB * 128 + c];
    }
  }
}

#define ACC8(u, a)                                            \
  {                                                           \
    _Pragma("unroll") for (int q = 0; q < 4; ++q) {           \
      union { unsigned w; float f; } lo_, hi_;                \
      lo_.w = (u)[q] << 16; hi_.w = (u)[q] & 0xffff0000u;     \
      (a)[2 * q] += lo_.f; (a)[2 * q + 1] += hi_.f;           \
    }                                                         \
  }

__device__ __forceinline__ int clampi(int q, int p0, int p1) {
  int t = q < p1 ? q : p0;
  return t < NEDGE ? t : 0;
}

// One wave per node handling BOTH relations; both node types in one dispatch.
__global__ __launch_bounds__(256) void gather2_k(
    const unsigned* __restrict__ src0, const unsigned* __restrict__ src1,
    const int* __restrict__ csr, const int* __restrict__ off,
    unsigned* __restrict__ m00, unsigned* __restrict__ m01,
    unsigned* __restrict__ m10, unsigned* __restrict__ m11) {
  int wv = __builtin_amdgcn_readfirstlane(threadIdx.x >> 6);
  int wid = blockIdx.x * 4 + wv;          // 0 .. 2*N_NODES-1
  int lane = threadIdx.x & 63;
  int type = wid >= N_NODES;
  int n = type ? wid - N_NODES : wid;
  const unsigned* src = type ? src1 : src0;
  const int* csrA = csr + (type ? 0 : 1) * NEDGE;
  const int* csrB = csr + (type ? 3 : 2) * NEDGE;
  const int* offA = off + (type ? 0 : 1) * (N_NODES + 1);
  const int* offB = off + (type ? 3 : 2) * (N_NODES + 1);
  unsigned* mA = type ? m10 : m00;
  unsigned* mB = type ? m11 : m01;
  int pA0 = offA[n], pA1 = offA[n + 1];
  int pB0 = offB[n], pB1 = offB[n + 1];
  int degA = pA1 - pA0, degB = pB1 - pB0;
  int rowg = lane >> 4;          // 0..3: row within each quad
  int colg = lane & 15;          // 16B slice: u32s colg*4 .. colg*4+3
  float a[8] = {}, b[8] = {};
  // fast path: first 8 edges of each relation, all loads issued up front
  {
    int ia0 = csrA[clampi(pA0 + rowg,     pA0, pA1)];
    int ia1 = csrA[clampi(pA0 + 4 + rowg, pA0, pA1)];
    int ib0 = csrB[clampi(pB0 + rowg,     pB0, pB1)];
    int ib1 = csrB[clampi(pB0 + 4 + rowg, pB0, pB1)];
    u32x4 ua0 = *(const u32x4*)(src + (size_t)ia0 * 64 + colg * 4);
    u32x4 ua1 = *(const u32x4*)(src + (size_t)ia1 * 64 + colg * 4);
    u32x4 ub0 = *(const u32x4*)(src + (size_t)ib0 * 64 + colg * 4);
    u32x4 ub1 = *(const u32x4*)(src + (size_t)ib1 * 64 + colg * 4);
    if (pA0 + rowg     < pA1) ACC8(ua0, a);
    if (pA0 + 4 + rowg < pA1) ACC8(ua1, a);
    if (pB0 + rowg     < pB1) ACC8(ub0, b);
    if (pB0 + 4 + rowg < pB1) ACC8(ub1, b);
  }
  for (int p = pA0 + 8; p < pA1; p += 8) {
    int i0 = csrA[clampi(p + rowg,     pA0, pA1)];
    int i1 = csrA[clampi(p + 4 + rowg, pA0, pA1)];
    u32x4 u0 = *(const u32x4*)(src + (size_t)i0 * 64 + colg * 4);
    u32x4 u1 = *(const u32x4*)(src + (size_t)i1 * 64 + colg * 4);
    if (p + rowg     < pA1) ACC8(u0, a);
    if (p + 4 + rowg < pA1) ACC8(u1, a);
  }
  for (int p = pB0 + 8; p < pB1; p += 8) {
    int i0 = csrB[clampi(p + rowg,     pB0, pB1)];
    int i1 = csrB[clampi(p + 4 + rowg, pB0, pB1)];
    u32x4 u0 = *(const u32x4*)(src + (size_t)i0 * 64 + colg * 4);
    u32x4 u1 = *(const u32x4*)(src + (size_t)i1 * 64 + colg * 4);
    if (p + rowg     < pB1) ACC8(u0, b);
    if (p + 4 + rowg < pB1) ACC8(u1, b);
  }
#pragma unroll
  for (int q = 0; q < 8; ++q) {
    a[q] += __shfl_xor(a[q], 16); a[q] += __shfl_xor(a[q], 32);
    b[q] += __shfl_xor(b[q], 16); b[q] += __shfl_xor(b[q], 32);
  }
  if (rowg == 0) {
    float invA = 1.0f / (float)(degA > 1 ? degA : 1);
    float invB = 1.0f / (float)(degB > 1 ? degB : 1);
    u32x4 wa, wb;
#pragma unroll
    for (int q = 0; q < 4; ++q) {
      wa[q] = cvtpk(a[2 * q] * invA, a[2 * q + 1] * invA);
      wb[q] = cvtpk(b[2 * q] * invB, b[2 * q + 1] * invB);
    }
    *(u32x4*)(mA + (size_t)n * 64 + colg * 4) = wa;
    *(u32x4*)(mB + (size_t)n * 64 + colg * 4) = wb;
  }
}

// LDS-staged GEMM with issue-early/write-late double-buffer (r13 structure).
template<int OUT_RELU_BF16>
__global__ __launch_bounds__(256) void gemm2_k(
    const short* __restrict__ self0, const short* __restrict__ self1,
    const short* __restrict__ mA0, const short* __restrict__ mB0,
    const short* __restrict__ mA1, const short* __restrict__ mB1,
    const short* __restrict__ WTpL, const float* __restrict__ biascL,
    void* __restrict__ out0, void* __restrict__ out1) {
  __shared__ short Wlds[2][8192];   // 2 x 16KB (2 k-steps each)
  int type = blockIdx.y;
  const short* selfp = type ? self1 : self0;
  const short* meanA = type ? mA1 : mA0;
  const short* meanB = type ? mB1 : mB0;
  const short* WTp = WTpL + type * 49152;
  const float* biasc = biascL + type * 128;
  void* outp = type ? out1 : out0;
  int tid = threadIdx.x;
  int lane = tid & 63, wave = tid >> 6;
  int rowbase = blockIdx.x * 128 + wave * 32;
  int r0 = rowbase + (lane & 15), r1 = r0 + 16;
  int rc0 = r0 < N_NODES ? r0 : N_NODES - 1;
  int rc1 = r1 < N_NODES ? r1 : N_NODES - 1;
  int kg = lane >> 4;
  f32x4 acc[2][8] = {};
  const f32x4* Wsrc = (const f32x4*)WTp;   // 6 chunks x 1024 f32x4
  f32x4 st[4];
#pragma unroll
  for (int j = 0; j < 4; ++j) st[j] = Wsrc[tid + j * 256];
  {
    f32x4* d = (f32x4*)Wlds[0];
#pragma unroll
    for (int j = 0; j < 4; ++j) d[tid + j * 256] = st[j];
  }
  __syncthreads();
  for (int c = 0; c < 6; ++c) {
    if (c < 5) {
#pragma unroll
      for (int j = 0; j < 4; ++j) st[j] = Wsrc[(c + 1) * 1024 + tid + j * 256];
    }
    const short* mp = (c < 2) ? selfp : ((c < 4) ? meanA : meanB);
    const short* wbase = Wlds[c & 1];
#pragma unroll
    for (int kh = 0; kh < 2; ++kh) {
      int kk = (c * 2 + kh) & 3;
      int kin = kk * 32 + kg * 8;
      bf16x8 a0 = *(const bf16x8*)(mp + (size_t)rc0 * 128 + kin);
      bf16x8 a1 = *(const bf16x8*)(mp + (size_t)rc1 * 128 + kin);
      const short* wb = wbase + kh * 4096 + lane * 8;
#pragma unroll
      for (int n0 = 0; n0 < 8; ++n0) {
        bf16x8 b = *(const bf16x8*)(wb + n0 * 512);
        acc[0][n0] = __builtin_amdgcn_mfma_f32_16x16x32_bf16(a0, b, acc[0][n0], 0, 0, 0);
        acc[1][n0] = __builtin_amdgcn_mfma_f32_16x16x32_bf16(a1, b, acc[1][n0], 0, 0, 0);
      }
    }
    if (c < 5) {
      f32x4* d = (f32x4*)Wlds[(c + 1) & 1];
#pragma unroll
      for (int j = 0; j < 4; ++j) d[tid + j * 256] = st[j];
    }
    __syncthreads();
  }
  int colb = lane & 15, rloc = kg * 4;
#pragma unroll
  for (int mt = 0; mt < 2; ++mt) {
    int rb = rowbase + mt * 16 + rloc;
#pragma unroll
    for (int n0 = 0; n0 < 8; ++n0) {
      int cc = n0 * 16 + colb;
      float bv = biasc[cc];
#pragma unroll
      for (int j = 0; j < 4; ++j) {
        int rr = rb + j;
        if (rr < N_NODES) {
          float v = acc[mt][n0][j] + bv;
          if (OUT_RELU_BF16) {
            ((short*)outp)[(size_t)rr * 128 + cc] = f2bf(v > 0.f ? v : 0.f);
          } else {
            __builtin_nontemporal_store(v, (float*)outp + (size_t)rr * 128 + cc);
          }
        }
      }
    }
  }
}

extern "C" void kernel_launch(void* const* d_in, const int* in_sizes, int n_in,
                              void* d_out, int out_size, void* d_ws, size_t ws_size,
                              hipStream_t stream) {
  (void)in_sizes; (void)n_in; (void)out_size; (void)ws_size;
  const float* xq  = (const float*)d_in[0];
  const float* xp  = (const float*)d_in[1];
  const int*   src = (const int*)d_in[2];
  const int*   dst = (const int*)d_in[3];
  const float* Ws1 = (const float*)d_in[4];
  const float* Wn1 = (const float*)d_in[5];
  const float* b1  = (const float*)d_in[6];
  const float* Ws2 = (const float*)d_in[7];
  const float* Wn2 = (const float*)d_in[8];
  const float* b2  = (const float*)d_in[9];

  char* w = (char*)d_ws;
  int*   cnt    = (int*)w;      w += (size_t)4 * N_NODES * 4;
  int*   bincnt = (int*)w;      w += 4096;
  int*   bsum   = (int*)w;      w += 4 * 256 * 4;
  int*   off    = (int*)w;      w += (size_t)4 * (N_NODES + 1) * 4;
  int*   csr    = (int*)w;      w += (size_t)4 * NEDGE * 4;
  short* meanA  = (short*)w;    w += (size_t)N_NODES * 128 * 2;
  short* meanB  = (short*)w;    w += (size_t)N_NODES * 128 * 2;
  short* h1q    = (short*)w;    w += (size_t)N_NODES * 128 * 2;
  short* h1p    = (short*)w;    w += (size_t)N_NODES * 128 * 2;
  short* xqb    = (short*)w;    w += (size_t)N_NODES * 128 * 2;
  short* xpb    = (short*)w;    w += (size_t)N_NODES * 128 * 2;
  short* WTp    = (short*)w;    w += (size_t)4 * 49152 * 2;
  float* biasc  = (float*)w;    w += 512 * 4;
  // staging (packed u32) only live during CSR build, aliases meanA:
  unsigned* stage = (unsigned*)meanA;   // 4*196*3456*4B = 10.8MB <= 25.6MB
  // type-1 mean buffers alias dead storage (fully overwritten before read):
  unsigned* mL1C = (unsigned*)d_out;                 // L1: d_out is scratch
  unsigned* mL1D = mL1C + (size_t)N_NODES * 64;
  unsigned* mL2C = (unsigned*)xqb;                   // L2: xqb/xpb are dead
  unsigned* mL2D = (unsigned*)xpb;

  dim3 b256(256);
  const int bgrid = (NEDGE + 2047) / 2048;        // 293
  const int ggrid = (N_NODES + 127) / 128;        // 782
  const int wgrid = 2 * N_NODES / 4;              // 50000 (wave per node+type)

  // --- CSR build via bucket counting-sort (no per-edge global atomics)
  hipMemsetAsync(bincnt, 0, 4096, stream);
  bin_k<<<dim3(bgrid, 4), b256, 0, stream>>>(src, dst, bincnt, stage);
  hist_k<<<dim3(NBUCK, 4), b256, 0, stream>>>(stage, bincnt, cnt, bsum);
  scan2_k<<<dim3(1), b256, 0, stream>>>(bsum);
  scan3_k<<<dim3(NBUCK, 4), b256, 0, stream>>>(cnt, bsum, off);
  place_k<<<dim3(NBUCK, 4), b256, 0, stream>>>(stage, bincnt, off, csr);
  fatprep_k<<<dim3(2 * CGRID + WGRID + 1), b256, 0, stream>>>(
      xq, xp, (unsigned*)xqb, (unsigned*)xpb,
      Ws1, Wn1, Ws2, Wn2, WTp, b1, b2, biasc);

  // ---- Layer 1: one gather (both types), one gemm (both types)
  gather2_k<<<wgrid, b256, 0, stream>>>((const unsigned*)xpb, (const unsigned*)xqb,
      csr, off, (unsigned*)meanA, (unsigned*)meanB, mL1C, mL1D);
  gemm2_k<1><<<dim3(ggrid, 2), b256, 0, stream>>>(
      xqb, xpb, meanA, meanB, (const short*)mL1C, (const short*)mL1D,
      WTp, biasc, h1q, h1p);

  // ---- Layer 2
  gather2_k<<<wgrid, b256, 0, stream>>>((const unsigned*)h1p, (const unsigned*)h1q,
      csr, off, (unsigned*)meanA, (unsigned*)meanB, mL2C, mL2D);
  gemm2_k<0><<<dim3(ggrid, 2), b256, 0, stream>>>(
      h1q, h1p, meanA, meanB, (const short*)mL2C, (const short*)mL2D,
      WTp + 2 * 49152, biasc + 256,
      (float*)d_out, (float*)d_out + (size_t)N_NODES * 128);
}

// Round 16
// 452.125 us; speedup vs baseline: 1.0792x; 1.0210x over previous
//
#include <hip/hip_runtime.h>
#include <hip/hip_bf16.h>

#define N_NODES 100000
#define NEDGE   600000
#define BSHIFT  9             // bucket = dst >> 9 (512 nodes/bucket)
#define NBUCK   196           // ceil(N_NODES / 512)
#define BCAP    3456          // per (rel,bucket) staging cap (mean 3061 + 7 sigma)
#define CGRID   6250          // N_NODES*16/256 (cvt blocks per type)
#define WGRID   96            // weight-pack blocks: 24576 tids * 8 shorts = 196608
#define BINGRID 1172          // 293 chunks x 4 rels

typedef __attribute__((ext_vector_type(8))) short bf16x8;
typedef __attribute__((ext_vector_type(4))) short s16x4;
typedef __attribute__((ext_vector_type(4))) float f32x4;
typedef __attribute__((ext_vector_type(4))) unsigned u32x4;

__device__ __forceinline__ short f2bf(float f) {
  union { float f; unsigned u; } x; x.f = f;
  unsigned r = x.u + 0x7FFFu + ((x.u >> 16) & 1u);
  return (short)(r >> 16);
}

// packed bf16 convert: D = [bf16(lo), bf16(hi)] in one instruction (RNE)
__device__ __forceinline__ unsigned cvtpk(float lo, float hi) {
  unsigned r;
  asm("v_cvt_pk_bf16_f32 %0, %1, %2" : "=v"(r) : "v"(lo), "v"(hi));
  return r;
}

// Merged first-wave dispatch: edge binning + cvt(xq,xp) + weight pack + bias.
// All regions independent; one dispatch removes 1 launch gap and overlaps
// bin's LDS-atomic work with cvt's streaming reads.
__global__ __launch_bounds__(256) void bin_fatprep_k(
    const int* __restrict__ sidx, const int* __restrict__ didx,
    int* __restrict__ bincnt, unsigned* __restrict__ stage,
    const float* __restrict__ xq, const float* __restrict__ xp,
    unsigned* __restrict__ xqb, unsigned* __restrict__ xpb,
    const float* __restrict__ Ws1, const float* __restrict__ Wn1,
    const float* __restrict__ Ws2, const float* __restrict__ Wn2,
    short* __restrict__ WTp,
    const float* __restrict__ b1, const float* __restrict__ b2,
    float* __restrict__ biasc) {
  __shared__ int hist[NBUCK];
  __shared__ int base[NBUCK];
  int bb = blockIdx.x, t = threadIdx.x;
  if (bb < BINGRID) {
    // ---- bin: chunk c of relation r
    int r = bb & 3, c = bb >> 2;
    int e0 = c * 2048 + t;
    const int* dd = didx + (size_t)r * NEDGE;
    const int* ss = sidx + (size_t)r * NEDGE;
    for (int i = t; i < NBUCK; i += 256) hist[i] = 0;
    __syncthreads();
    unsigned pv[8]; int bu[8], lr[8];
#pragma unroll
    for (int j = 0; j < 8; ++j) {
      int e = e0 + j * 256;
      if (e < NEDGE) {
        int dv = dd[e];
        bu[j] = dv >> BSHIFT;
        pv[j] = (unsigned)ss[e] | ((unsigned)(dv & 511) << 17);
        lr[j] = atomicAdd(&hist[bu[j]], 1);     // LDS atomic
      }
    }
    __syncthreads();
    for (int i = t; i < NBUCK; i += 256)
      base[i] = atomicAdd(&bincnt[r * NBUCK + i], hist[i]);
    __syncthreads();
#pragma unroll
    for (int j = 0; j < 8; ++j) {
      int e = e0 + j * 256;
      if (e < NEDGE)
        stage[(size_t)(r * NBUCK + bu[j]) * BCAP + base[bu[j]] + lr[j]] = pv[j];
    }
    return;
  }
  int b = bb - BINGRID;
  if (b < 2 * CGRID) {
    // ---- f32 -> packed bf16
    const float* x = (b < CGRID) ? xq : xp;
    unsigned* o = (b < CGRID) ? xqb : xpb;
    int i = (b < CGRID ? b : b - CGRID) * 256 + t;
    f32x4 v0 = ((const f32x4*)x)[i * 2];
    f32x4 v1 = ((const f32x4*)x)[i * 2 + 1];
    ((u32x4*)o)[i] = (u32x4){cvtpk(v0[0], v0[1]), cvtpk(v0[2], v0[3]),
                             cvtpk(v1[0], v1[1]), cvtpk(v1[2], v1[3])};
  } else if (b < 2 * CGRID + WGRID) {
    // ---- pack combined weights into MFMA B-fragment-linear layout
    int tid = (b - 2 * CGRID) * 256 + t;  // 0..24575 (exact, no OOB)
    int lane = tid & 63;
    int n0 = (tid >> 6) & 7;
    int idx3 = tid >> 9;                  // 0..47 = lt*12 + k0
    int k0 = idx3 % 12;
    int lt = idx3 / 12;
    int l = lt >> 1, ty = lt & 1;
    const float* Wself  = l ? Ws2 : Ws1;
    const float* Wneigh = l ? Wn2 : Wn1;
    int rA = ty ? 0 : 1, rB = ty ? 3 : 2;
    int n = n0 * 16 + (lane & 15);
    int kbase = k0 * 32 + (lane >> 4) * 8;
    short out[8];
#pragma unroll
    for (int j = 0; j < 8; ++j) {
      int k = kbase + j;
      int kk = k & 127, blk = k >> 7;
      float v;
      if (blk == 0)      v = Wself[rA * 16384 + kk * 128 + n] + Wself[rB * 16384 + kk * 128 + n];
      else if (blk == 1) v = Wneigh[rA * 16384 + kk * 128 + n];
      else               v = Wneigh[rB * 16384 + kk * 128 + n];
      out[j] = f2bf(v);
    }
    s16x4* dst = (s16x4*)&WTp[tid * 8];
    dst[0] = *(s16x4*)&out[0];
    dst[1] = *(s16x4*)&out[4];
  } else {
    // ---- bias combine: 512 items with 256 threads (2 each)
#pragma unroll
    for (int q = 0; q < 2; ++q) {
      int tid = t + q * 256;
      int l = tid >> 8, ty = (tid >> 7) & 1, c = tid & 127;
      const float* bbp = l ? b2 : b1;
      int rA = ty ? 0 : 1, rB = ty ? 3 : 2;
      biasc[tid] = bbp[rA * 128 + c] + bbp[rB * 128 + c];
    }
  }
}

// Phase B: one block per (bucket, rel): LDS histogram -> cnt (coalesced)
// AND bucket total -> bucketsum.
__global__ __launch_bounds__(256) void hist_k(const unsigned* __restrict__ stage,
                                              const int* __restrict__ bincnt,
                                              int* __restrict__ cnt,
                                              int* __restrict__ bucketsum) {
  __shared__ int h[512];
  __shared__ int red[256];
  int bu = blockIdx.x, r = blockIdx.y, t = threadIdx.x;
  int len = bincnt[r * NBUCK + bu];
  const unsigned* sg = stage + (size_t)(r * NBUCK + bu) * BCAP;
  h[t] = 0; h[t + 256] = 0;
  __syncthreads();
  for (int i = t; i < len; i += 256) atomicAdd(&h[sg[i] >> 17], 1);  // LDS
  __syncthreads();
  int lo = bu << BSHIFT;
  int d0 = lo + t;
  if (d0 < N_NODES)       cnt[r * N_NODES + d0]       = h[t];
  if (d0 + 256 < N_NODES) cnt[r * N_NODES + d0 + 256] = h[t + 256];
  red[t] = h[t] + h[t + 256];
  __syncthreads();
  for (int st = 128; st > 0; st >>= 1) {
    if (t < st) red[t] += red[t + st];
    __syncthreads();
  }
  if (t == 0) bucketsum[r * NBUCK + bu] = red[0];
}

// exclusive scan of the 196 bucket sums per relation. 1 block, 256 thr.
__global__ __launch_bounds__(256) void scan2_k(int* __restrict__ bucketsum) {
  __shared__ int buf[256];
  int t = threadIdx.x;
  for (int r = 0; r < 4; ++r) {
    int v = (t < NBUCK) ? bucketsum[r * NBUCK + t] : 0;
    buf[t] = v;
    __syncthreads();
    for (int st = 1; st < 256; st <<= 1) {
      int x = (t >= st) ? buf[t - st] : 0;
      __syncthreads();
      buf[t] += x;
      __syncthreads();
    }
    if (t < NBUCK) bucketsum[r * NBUCK + t] = buf[t] - v;   // exclusive
    __syncthreads();
  }
}

// Fused scan3+place: one block per (bucket, rel). Bucket-local exclusive scan
// of 512 counts -> off (for gather) AND immediate edge placement with
// LDS-only cursors (was two dispatches; off no longer round-trips).
__global__ __launch_bounds__(256) void scan3place_k(
    const int* __restrict__ cnt, const int* __restrict__ bucketsum,
    const unsigned* __restrict__ stage, const int* __restrict__ bincnt,
    int* __restrict__ off, int* __restrict__ csr) {
  __shared__ int ps[256];
  __shared__ int ofl[512];
  __shared__ int cur[512];
  int bu = blockIdx.x, r = blockIdx.y, t = threadIdx.x;
  int lo = bu << BSHIFT;
  int i0 = lo + 2 * t;
  int c0 = (i0 < N_NODES) ? cnt[r * N_NODES + i0] : 0;
  int c1 = (i0 + 1 < N_NODES) ? cnt[r * N_NODES + i0 + 1] : 0;
  int pair = c0 + c1;
  ps[t] = pair;
  __syncthreads();
  for (int st = 1; st < 256; st <<= 1) {
    int x = (t >= st) ? ps[t - st] : 0;
    __syncthreads();
    ps[t] += x;
    __syncthreads();
  }
  int base = bucketsum[r * NBUCK + bu] + ps[t] - pair;
  int* o = off + r * (N_NODES + 1);
  if (i0 < N_NODES)     o[i0]     = base;
  if (i0 + 1 < N_NODES) o[i0 + 1] = base + c0;
  if (bu == 0 && t == 0) o[N_NODES] = NEDGE;
  ofl[2 * t] = base;
  ofl[2 * t + 1] = base + c0;
  cur[t] = 0; cur[t + 256] = 0;
  __syncthreads();
  int len = bincnt[r * NBUCK + bu];
  const unsigned* sg = stage + (size_t)(r * NBUCK + bu) * BCAP;
  int* cs = csr + (size_t)r * NEDGE;
  for (int i = t; i < len; i += 256) {
    unsigned v = sg[i];
    int dl = v >> 17;
    int pos = ofl[dl] + atomicAdd(&cur[dl], 1);   // LDS atomic
    cs[pos] = (int)(v & 0x1FFFFu);
  }
}

#define ACC8(u, a)                                            \
  {                                                           \
    _Pragma("unroll") for (int q = 0; q < 4; ++q) {           \
      union { unsigned w; float f; } lo_, hi_;                \
      lo_.w = (u)[q] << 16; hi_.w = (u)[q] & 0xffff0000u;     \
      (a)[2 * q] += lo_.f; (a)[2 * q + 1] += hi_.f;           \
    }                                                         \
  }

__device__ __forceinline__ int clampi(int q, int p0, int p1) {
  int t = q < p1 ? q : p0;
  return t < NEDGE ? t : 0;
}

// One wave per node handling BOTH relations; both node types in one dispatch.
__global__ __launch_bounds__(256) void gather2_k(
    const unsigned* __restrict__ src0, const unsigned* __restrict__ src1,
    const int* __restrict__ csr, const int* __restrict__ off,
    unsigned* __restrict__ m00, unsigned* __restrict__ m01,
    unsigned* __restrict__ m10, unsigned* __restrict__ m11) {
  int wv = __builtin_amdgcn_readfirstlane(threadIdx.x >> 6);
  int wid = blockIdx.x * 4 + wv;          // 0 .. 2*N_NODES-1
  int lane = threadIdx.x & 63;
  int type = wid >= N_NODES;
  int n = type ? wid - N_NODES : wid;
  const unsigned* src = type ? src1 : src0;
  const int* csrA = csr + (type ? 0 : 1) * NEDGE;
  const int* csrB = csr + (type ? 3 : 2) * NEDGE;
  const int* offA = off + (type ? 0 : 1) * (N_NODES + 1);
  const int* offB = off + (type ? 3 : 2) * (N_NODES + 1);
  unsigned* mA = type ? m10 : m00;
  unsigned* mB = type ? m11 : m01;
  int pA0 = offA[n], pA1 = offA[n + 1];
  int pB0 = offB[n], pB1 = offB[n + 1];
  int degA = pA1 - pA0, degB = pB1 - pB0;
  int rowg = lane >> 4;          // 0..3: row within each quad
  int colg = lane & 15;          // 16B slice: u32s colg*4 .. colg*4+3
  float a[8] = {}, b[8] = {};
  // fast path: first 8 edges of each relation, all loads issued up front
  {
    int ia0 = csrA[clampi(pA0 + rowg,     pA0, pA1)];
    int ia1 = csrA[clampi(pA0 + 4 + rowg, pA0, pA1)];
    int ib0 = csrB[clampi(pB0 + rowg,     pB0, pB1)];
    int ib1 = csrB[clampi(pB0 + 4 + rowg, pB0, pB1)];
    u32x4 ua0 = *(const u32x4*)(src + (size_t)ia0 * 64 + colg * 4);
    u32x4 ua1 = *(const u32x4*)(src + (size_t)ia1 * 64 + colg * 4);
    u32x4 ub0 = *(const u32x4*)(src + (size_t)ib0 * 64 + colg * 4);
    u32x4 ub1 = *(const u32x4*)(src + (size_t)ib1 * 64 + colg * 4);
    if (pA0 + rowg     < pA1) ACC8(ua0, a);
    if (pA0 + 4 + rowg < pA1) ACC8(ua1, a);
    if (pB0 + rowg     < pB1) ACC8(ub0, b);
    if (pB0 + 4 + rowg < pB1) ACC8(ub1, b);
  }
  for (int p = pA0 + 8; p < pA1; p += 8) {
    int i0 = csrA[clampi(p + rowg,     pA0, pA1)];
    int i1 = csrA[clampi(p + 4 + rowg, pA0, pA1)];
    u32x4 u0 = *(const u32x4*)(src + (size_t)i0 * 64 + colg * 4);
    u32x4 u1 = *(const u32x4*)(src + (size_t)i1 * 64 + colg * 4);
    if (p + rowg     < pA1) ACC8(u0, a);
    if (p + 4 + rowg < pA1) ACC8(u1, a);
  }
  for (int p = pB0 + 8; p < pB1; p += 8) {
    int i0 = csrB[clampi(p + rowg,     pB0, pB1)];
    int i1 = csrB[clampi(p + 4 + rowg, pB0, pB1)];
    u32x4 u0 = *(const u32x4*)(src + (size_t)i0 * 64 + colg * 4);
    u32x4 u1 = *(const u32x4*)(src + (size_t)i1 * 64 + colg * 4);
    if (p + rowg     < pB1) ACC8(u0, b);
    if (p + 4 + rowg < pB1) ACC8(u1, b);
  }
#pragma unroll
  for (int q = 0; q < 8; ++q) {
    a[q] += __shfl_xor(a[q], 16); a[q] += __shfl_xor(a[q], 32);
    b[q] += __shfl_xor(b[q], 16); b[q] += __shfl_xor(b[q], 32);
  }
  if (rowg == 0) {
    float invA = 1.0f / (float)(degA > 1 ? degA : 1);
    float invB = 1.0f / (float)(degB > 1 ? degB : 1);
    u32x4 wa, wb;
#pragma unroll
    for (int q = 0; q < 4; ++q) {
      wa[q] = cvtpk(a[2 * q] * invA, a[2 * q + 1] * invA);
      wb[q] = cvtpk(b[2 * q] * invB, b[2 * q + 1] * invB);
    }
    *(u32x4*)(mA + (size_t)n * 64 + colg * 4) = wa;
    *(u32x4*)(mB + (size_t)n * 64 + colg * 4) = wb;
  }
}

// LDS-staged GEMM, 64-ROW TILES (tail fix): 3126 blocks over ~1280 resident
// slots = 81% last-round utilization (128-row tiles gave 61%). Each wave owns
// one 16-row m-frag; issue-early/write-late W double-buffer kept.
template<int OUT_RELU_BF16>
__global__ __launch_bounds__(256) void gemm2_k(
    const short* __restrict__ self0, const short* __restrict__ self1,
    const short* __restrict__ mA0, const short* __restrict__ mB0,
    const short* __restrict__ mA1, const short* __restrict__ mB1,
    const short* __restrict__ WTpL, const float* __restrict__ biascL,
    void* __restrict__ out0, void* __restrict__ out1) {
  __shared__ short Wlds[2][8192];   // 2 x 16KB (2 k-steps each)
  int type = blockIdx.y;
  const short* selfp = type ? self1 : self0;
  const short* meanA = type ? mA1 : mA0;
  const short* meanB = type ? mB1 : mB0;
  const short* WTp = WTpL + type * 49152;
  const float* biasc = biascL + type * 128;
  void* outp = type ? out1 : out0;
  int tid = threadIdx.x;
  int lane = tid & 63, wave = tid >> 6;
  int rowbase = blockIdx.x * 64 + wave * 16;
  int r0 = rowbase + (lane & 15);
  int rc0 = r0 < N_NODES ? r0 : N_NODES - 1;
  int kg = lane >> 4;
  f32x4 acc[8] = {};
  const f32x4* Wsrc = (const f32x4*)WTp;   // 6 chunks x 1024 f32x4
  f32x4 st[4];
#pragma unroll
  for (int j = 0; j < 4; ++j) st[j] = Wsrc[tid + j * 256];
  {
    f32x4* d = (f32x4*)Wlds[0];
#pragma unroll
    for (int j = 0; j < 4; ++j) d[tid + j * 256] = st[j];
  }
  __syncthreads();
  for (int c = 0; c < 6; ++c) {
    if (c < 5) {
#pragma unroll
      for (int j = 0; j < 4; ++j) st[j] = Wsrc[(c + 1) * 1024 + tid + j * 256];
    }
    const short* mp = (c < 2) ? selfp : ((c < 4) ? meanA : meanB);
    const short* wbase = Wlds[c & 1];
#pragma unroll
    for (int kh = 0; kh < 2; ++kh) {
      int kk = (c * 2 + kh) & 3;
      int kin = kk * 32 + kg * 8;
      bf16x8 a0 = *(const bf16x8*)(mp + (size_t)rc0 * 128 + kin);
      const short* wb = wbase + kh * 4096 + lane * 8;
#pragma unroll
      for (int n0 = 0; n0 < 8; ++n0) {
        bf16x8 b = *(const bf16x8*)(wb + n0 * 512);
        acc[n0] = __builtin_amdgcn_mfma_f32_16x16x32_bf16(a0, b, acc[n0], 0, 0, 0);
      }
    }
    if (c < 5) {
      f32x4* d = (f32x4*)Wlds[(c + 1) & 1];
#pragma unroll
      for (int j = 0; j < 4; ++j) d[tid + j * 256] = st[j];
    }
    __syncthreads();
  }
  int colb = lane & 15, rloc = kg * 4;
  int rb = rowbase + rloc;
#pragma unroll
  for (int n0 = 0; n0 < 8; ++n0) {
    int cc = n0 * 16 + colb;
    float bv = biasc[cc];
#pragma unroll
    for (int j = 0; j < 4; ++j) {
      int rr = rb + j;
      if (rr < N_NODES) {
        float v = acc[n0][j] + bv;
        if (OUT_RELU_BF16) {
          ((short*)outp)[(size_t)rr * 128 + cc] = f2bf(v > 0.f ? v : 0.f);
        } else {
          __builtin_nontemporal_store(v, (float*)outp + (size_t)rr * 128 + cc);
        }
      }
    }
  }
}

extern "C" void kernel_launch(void* const* d_in, const int* in_sizes, int n_in,
                              void* d_out, int out_size, void* d_ws, size_t ws_size,
                              hipStream_t stream) {
  (void)in_sizes; (void)n_in; (void)out_size; (void)ws_size;
  const float* xq  = (const float*)d_in[0];
  const float* xp  = (const float*)d_in[1];
  const int*   src = (const int*)d_in[2];
  const int*   dst = (const int*)d_in[3];
  const float* Ws1 = (const float*)d_in[4];
  const float* Wn1 = (const float*)d_in[5];
  const float* b1  = (const float*)d_in[6];
  const float* Ws2 = (const float*)d_in[7];
  const float* Wn2 = (const float*)d_in[8];
  const float* b2  = (const float*)d_in[9];

  char* w = (char*)d_ws;
  int*   cnt    = (int*)w;      w += (size_t)4 * N_NODES * 4;
  int*   bincnt = (int*)w;      w += 4096;
  int*   bsum   = (int*)w;      w += 4 * 256 * 4;
  int*   off    = (int*)w;      w += (size_t)4 * (N_NODES + 1) * 4;
  int*   csr    = (int*)w;      w += (size_t)4 * NEDGE * 4;
  short* meanA  = (short*)w;    w += (size_t)N_NODES * 128 * 2;
  short* meanB  = (short*)w;    w += (size_t)N_NODES * 128 * 2;
  short* h1q    = (short*)w;    w += (size_t)N_NODES * 128 * 2;
  short* h1p    = (short*)w;    w += (size_t)N_NODES * 128 * 2;
  short* xqb    = (short*)w;    w += (size_t)N_NODES * 128 * 2;
  short* xpb    = (short*)w;    w += (size_t)N_NODES * 128 * 2;
  short* WTp    = (short*)w;    w += (size_t)4 * 49152 * 2;
  float* biasc  = (float*)w;    w += 512 * 4;
  // staging (packed u32) only live during CSR build, aliases meanA:
  unsigned* stage = (unsigned*)meanA;   // 4*196*3456*4B = 10.8MB <= 25.6MB
  // type-1 mean buffers alias dead storage (fully overwritten before read):
  unsigned* mL1C = (unsigned*)d_out;                 // L1: d_out is scratch
  unsigned* mL1D = mL1C + (size_t)N_NODES * 64;
  unsigned* mL2C = (unsigned*)xqb;                   // L2: xqb/xpb are dead
  unsigned* mL2D = (unsigned*)xpb;

  dim3 b256(256);
  const int ggrid = (N_NODES + 63) / 64;          // 1563 (64-row tiles)
  const int wgrid = 2 * N_NODES / 4;              // 50000 (wave per node+type)

  // --- CSR build + prep (merged first wave), then count-sort chain
  hipMemsetAsync(bincnt, 0, 4096, stream);
  bin_fatprep_k<<<dim3(BINGRID + 2 * CGRID + WGRID + 1), b256, 0, stream>>>(
      src, dst, bincnt, stage, xq, xp, (unsigned*)xqb, (unsigned*)xpb,
      Ws1, Wn1, Ws2, Wn2, WTp, b1, b2, biasc);
  hist_k<<<dim3(NBUCK, 4), b256, 0, stream>>>(stage, bincnt, cnt, bsum);
  scan2_k<<<dim3(1), b256, 0, stream>>>(bsum);
  scan3place_k<<<dim3(NBUCK, 4), b256, 0, stream>>>(cnt, bsum, stage, bincnt,
                                                    off, csr);

  // ---- Layer 1: one gather (both types), one gemm (both types)
  gather2_k<<<wgrid, b256, 0, stream>>>((const unsigned*)xpb, (const unsigned*)xqb,
      csr, off, (unsigned*)meanA, (unsigned*)meanB, mL1C, mL1D);
  gemm2_k<1><<<dim3(ggrid, 2), b256, 0, stream>>>(
      xqb, xpb, meanA, meanB, (const short*)mL1C, (const short*)mL1D,
      WTp, biasc, h1q, h1p);

  // ---- Layer 2
  gather2_k<<<wgrid, b256, 0, stream>>>((const unsigned*)h1p, (const unsigned*)h1q,
      csr, off, (unsigned*)meanA, (unsigned*)meanB, mL2C, mL2D);
  gemm2_k<0><<<dim3(ggrid, 2), b256, 0, stream>>>(
      h1q, h1p, meanA, meanB, (const short*)mL2C, (const short*)mL2D,
      WTp + 2 * 49152, biasc + 256,
      (float*)d_out, (float*)d_out + (size_t)N_NODES * 128);
}